// Round 1
// baseline (187.658 us; speedup 1.0000x reference)
//
#include <hip/hip_runtime.h>
#include <hip/hip_bf16.h>

#define BLOCK   256
#define QPT     8      // queries per thread
#define DCHUNKS 32     // db split into this many chunks (grid.y)
#define CHUNK   512    // db points per chunk = 16384/32

// One pass: for each query point, min squared distance to all db points.
// Uses the gram form d2 = |q|^2 + |p|^2 - 2 q.p to match the reference
// formula and minimize VALU ops (3 fma + add + fma + min per pair).
__global__ __launch_bounds__(BLOCK) void chamfer_pass(
    const float* __restrict__ q, const float* __restrict__ db,
    unsigned* __restrict__ minOut, int nQ, int nDb)
{
    __shared__ float4 tile[CHUNK];

    const int qbase = blockIdx.x * (BLOCK * QPT);
    const int dbase = blockIdx.y * CHUNK;

    // Stage db chunk into LDS as (x, y, z, |p|^2)
    for (int i = threadIdx.x; i < CHUNK; i += BLOCK) {
        int gi = dbase + i;
        float px = db[gi * 3 + 0];
        float py = db[gi * 3 + 1];
        float pz = db[gi * 3 + 2];
        tile[i] = make_float4(px, py, pz, px * px + py * py + pz * pz);
    }
    __syncthreads();

    // Load this thread's QPT query points into registers
    float qx[QPT], qy[QPT], qz[QPT], q2[QPT], mn[QPT];
#pragma unroll
    for (int k = 0; k < QPT; ++k) {
        int qi = qbase + k * BLOCK + threadIdx.x;
        float x = q[qi * 3 + 0];
        float y = q[qi * 3 + 1];
        float z = q[qi * 3 + 2];
        qx[k] = x; qy[k] = y; qz[k] = z;
        q2[k] = x * x + y * y + z * z;
        mn[k] = 3.4e38f;
    }

    // Inner loop: broadcast LDS read of one db point, update 8 queries
#pragma unroll 4
    for (int j = 0; j < CHUNK; ++j) {
        float4 p = tile[j];
#pragma unroll
        for (int k = 0; k < QPT; ++k) {
            float t = qx[k] * p.x + qy[k] * p.y + qz[k] * p.z; // 3 fma
            float d = (q2[k] + p.w) - 2.0f * t;                // add + fma
            mn[k] = fminf(mn[k], d);                           // min
        }
    }

    // One atomic per query per chunk; d2 >= 0 so uint compare == float compare
#pragma unroll
    for (int k = 0; k < QPT; ++k) {
        float m = fmaxf(mn[k], 0.0f);
        atomicMin(&minOut[qbase + k * BLOCK + threadIdx.x], __float_as_uint(m));
    }
}

__global__ __launch_bounds__(1024) void chamfer_reduce(
    const unsigned* __restrict__ minC, const unsigned* __restrict__ minT,
    float* __restrict__ out, int n, int m)
{
    __shared__ float redA[16], redB[16];
    float sA = 0.0f, sB = 0.0f;
    for (int i = threadIdx.x; i < n; i += 1024) sA += __uint_as_float(minC[i]);
    for (int i = threadIdx.x; i < m; i += 1024) sB += __uint_as_float(minT[i]);

    // wave(64) reduction
#pragma unroll
    for (int off = 32; off > 0; off >>= 1) {
        sA += __shfl_down(sA, off, 64);
        sB += __shfl_down(sB, off, 64);
    }
    int wave = threadIdx.x >> 6;
    int lane = threadIdx.x & 63;
    if (lane == 0) { redA[wave] = sA; redB[wave] = sB; }
    __syncthreads();
    if (threadIdx.x == 0) {
        float tA = 0.0f, tB = 0.0f;
        for (int w = 0; w < 16; ++w) { tA += redA[w]; tB += redB[w]; }
        out[0] = tA / (float)n + tB / (float)m;
    }
}

extern "C" void kernel_launch(void* const* d_in, const int* in_sizes, int n_in,
                              void* d_out, int out_size, void* d_ws, size_t ws_size,
                              hipStream_t stream) {
    const float* Xc = (const float*)d_in[0];
    const float* Xt = (const float*)d_in[1];
    const int n = in_sizes[0] / 3;   // 16384
    const int m = in_sizes[1] / 3;   // 16384

    unsigned* minC = (unsigned*)d_ws;       // [n] mins over Xt for each Xc
    unsigned* minT = minC + n;              // [m] mins over Xc for each Xt

    // 0xFF bytes -> 0xFFFFFFFF, larger (as uint) than any finite float's bits
    hipMemsetAsync(d_ws, 0xFF, (size_t)(n + m) * sizeof(unsigned), stream);

    dim3 grid1(n / (BLOCK * QPT), DCHUNKS);
    chamfer_pass<<<grid1, BLOCK, 0, stream>>>(Xc, Xt, minC, n, m);

    dim3 grid2(m / (BLOCK * QPT), DCHUNKS);
    chamfer_pass<<<grid2, BLOCK, 0, stream>>>(Xt, Xc, minT, m, n);

    chamfer_reduce<<<1, 1024, 0, stream>>>(minC, minT, (float*)d_out, n, m);
}

// Round 2
// 110.104 us; speedup vs baseline: 1.7044x; 1.7044x over previous
//
#include <hip/hip_runtime.h>
#include <hip/hip_bf16.h>

#define BLOCK   256
#define QPT     8      // queries per thread
#define DCHUNKS 128    // db split into this many chunks (grid.y)
#define CHUNK   128    // db points per chunk = 16384/128

// Pack both clouds into float4 (x, y, z, |p|^2) so passes load 16B coalesced
// for both query and db roles.
__global__ __launch_bounds__(BLOCK) void chamfer_prep(
    const float* __restrict__ Xc, const float* __restrict__ Xt,
    float4* __restrict__ Pc, float4* __restrict__ Pt, int n, int m)
{
    int i = blockIdx.x * BLOCK + threadIdx.x;
    if (i < n) {
        float x = Xc[i * 3 + 0], y = Xc[i * 3 + 1], z = Xc[i * 3 + 2];
        Pc[i] = make_float4(x, y, z, x * x + y * y + z * z);
    }
    if (i < m) {
        float x = Xt[i * 3 + 0], y = Xt[i * 3 + 1], z = Xt[i * 3 + 2];
        Pt[i] = make_float4(x, y, z, x * x + y * y + z * z);
    }
}

// For each query point, min over db of (|p|^2 - 2 q.p). q^2 added in epilogue.
// Inner pair: 3 fma + shared min3 -> ~3.5 VALU insts per pair.
__global__ __launch_bounds__(BLOCK) void chamfer_pass(
    const float4* __restrict__ q, const float4* __restrict__ db,
    unsigned* __restrict__ minOut)
{
    __shared__ float4 tile[CHUNK];

    const int qbase = blockIdx.x * (BLOCK * QPT);
    const int dbase = blockIdx.y * CHUNK;

    // Stage db chunk into LDS (128 x 16B = 2 KB, one coalesced load)
    if (threadIdx.x < CHUNK) tile[threadIdx.x] = db[dbase + threadIdx.x];

    // This thread's QPT query points: premultiply by -2, keep q2 for epilogue
    float qx2[QPT], qy2[QPT], qz2[QPT], q2[QPT], mn[QPT];
#pragma unroll
    for (int k = 0; k < QPT; ++k) {
        float4 v = q[qbase + k * BLOCK + threadIdx.x];
        qx2[k] = -2.0f * v.x;
        qy2[k] = -2.0f * v.y;
        qz2[k] = -2.0f * v.z;
        q2[k]  = v.w;
        mn[k]  = 3.4e38f;
    }
    __syncthreads();

    // Two db points per iteration; fminf(fminf()) -> v_min3_f32
#pragma unroll 2
    for (int j = 0; j < CHUNK; j += 2) {
        float4 p0 = tile[j];
        float4 p1 = tile[j + 1];
#pragma unroll
        for (int k = 0; k < QPT; ++k) {
            float a0 = fmaf(qx2[k], p0.x, p0.w);
            a0 = fmaf(qy2[k], p0.y, a0);
            a0 = fmaf(qz2[k], p0.z, a0);
            float a1 = fmaf(qx2[k], p1.x, p1.w);
            a1 = fmaf(qy2[k], p1.y, a1);
            a1 = fmaf(qz2[k], p1.z, a1);
            mn[k] = fminf(mn[k], fminf(a0, a1));
        }
    }

    // d2 = max(mn + q2, 0) >= 0, so uint compare == float compare
#pragma unroll
    for (int k = 0; k < QPT; ++k) {
        float d = fmaxf(mn[k] + q2[k], 0.0f);
        atomicMin(&minOut[qbase + k * BLOCK + threadIdx.x], __float_as_uint(d));
    }
}

__global__ __launch_bounds__(1024) void chamfer_reduce(
    const unsigned* __restrict__ minC, const unsigned* __restrict__ minT,
    float* __restrict__ out, int n, int m)
{
    __shared__ float redA[16], redB[16];
    float sA = 0.0f, sB = 0.0f;
    for (int i = threadIdx.x; i < n; i += 1024) sA += __uint_as_float(minC[i]);
    for (int i = threadIdx.x; i < m; i += 1024) sB += __uint_as_float(minT[i]);

#pragma unroll
    for (int off = 32; off > 0; off >>= 1) {
        sA += __shfl_down(sA, off, 64);
        sB += __shfl_down(sB, off, 64);
    }
    int wave = threadIdx.x >> 6;
    int lane = threadIdx.x & 63;
    if (lane == 0) { redA[wave] = sA; redB[wave] = sB; }
    __syncthreads();
    if (threadIdx.x == 0) {
        float tA = 0.0f, tB = 0.0f;
        for (int w = 0; w < 16; ++w) { tA += redA[w]; tB += redB[w]; }
        out[0] = tA / (float)n + tB / (float)m;
    }
}

extern "C" void kernel_launch(void* const* d_in, const int* in_sizes, int n_in,
                              void* d_out, int out_size, void* d_ws, size_t ws_size,
                              hipStream_t stream) {
    const float* Xc = (const float*)d_in[0];
    const float* Xt = (const float*)d_in[1];
    const int n = in_sizes[0] / 3;   // 16384
    const int m = in_sizes[1] / 3;   // 16384

    // ws layout: minC[n] u32 | minT[m] u32 | Pc[n] float4 | Pt[m] float4
    unsigned* minC = (unsigned*)d_ws;
    unsigned* minT = minC + n;
    float4*   Pc   = (float4*)((char*)d_ws + (size_t)(n + m) * sizeof(unsigned));
    float4*   Pt   = Pc + n;

    hipMemsetAsync(d_ws, 0xFF, (size_t)(n + m) * sizeof(unsigned), stream);

    int prepBlocks = ((n > m ? n : m) + BLOCK - 1) / BLOCK;
    chamfer_prep<<<prepBlocks, BLOCK, 0, stream>>>(Xc, Xt, Pc, Pt, n, m);

    dim3 grid1(n / (BLOCK * QPT), DCHUNKS);
    chamfer_pass<<<grid1, BLOCK, 0, stream>>>(Pc, Pt, minC);

    dim3 grid2(m / (BLOCK * QPT), DCHUNKS);
    chamfer_pass<<<grid2, BLOCK, 0, stream>>>(Pt, Pc, minT);

    chamfer_reduce<<<1, 1024, 0, stream>>>(minC, minT, (float*)d_out, n, m);
}

// Round 3
// 98.404 us; speedup vs baseline: 1.9070x; 1.1189x over previous
//
#include <hip/hip_runtime.h>
#include <hip/hip_bf16.h>

#define BLOCK   256
#define QPT     8      // queries per thread
#define DCHUNKS 128    // db split into this many chunks (grid.y)
#define CHUNK   128    // db points per chunk = 16384/128

// Pack both clouds into float4 (x,y,z,|p|^2), init the min arrays to +inf
// bit-pattern, and zero the output accumulator (stream-ordered before reduce).
__global__ __launch_bounds__(BLOCK) void chamfer_prep(
    const float* __restrict__ Xc, const float* __restrict__ Xt,
    float4* __restrict__ Pc, float4* __restrict__ Pt,
    unsigned* __restrict__ minC, unsigned* __restrict__ minT,
    float* __restrict__ out, int n, int m)
{
    int i = blockIdx.x * BLOCK + threadIdx.x;
    if (i == 0) out[0] = 0.0f;
    if (i < n) {
        float x = Xc[i * 3 + 0], y = Xc[i * 3 + 1], z = Xc[i * 3 + 2];
        Pc[i] = make_float4(x, y, z, x * x + y * y + z * z);
        minC[i] = 0xFFFFFFFFu;
    }
    if (i < m) {
        float x = Xt[i * 3 + 0], y = Xt[i * 3 + 1], z = Xt[i * 3 + 2];
        Pt[i] = make_float4(x, y, z, x * x + y * y + z * z);
        minT[i] = 0xFFFFFFFFu;
    }
}

// Both chamfer directions in one launch: blockIdx.z selects (query,db) role.
// Tracks min over db of (|p|^2 - 2 q.p); q^2 added in the epilogue.
// Inner pair cost: 3 fma + 0.5 min3 = 3.5 VALU insts.
__global__ __launch_bounds__(BLOCK) void chamfer_pass(
    const float4* __restrict__ Pc, const float4* __restrict__ Pt,
    unsigned* __restrict__ minC, unsigned* __restrict__ minT)
{
    __shared__ float4 tile[CHUNK];

    const float4* q;
    const float4* db;
    unsigned* minOut;
    if (blockIdx.z == 0) { q = Pc; db = Pt; minOut = minC; }
    else                 { q = Pt; db = Pc; minOut = minT; }

    const int qbase = blockIdx.x * (BLOCK * QPT);
    const int dbase = blockIdx.y * CHUNK;

    // Stage db chunk into LDS (128 x 16B = 2 KB)
    if (threadIdx.x < CHUNK) tile[threadIdx.x] = db[dbase + threadIdx.x];

    // This thread's QPT query points: premultiply by -2, keep q2 for epilogue
    float qx2[QPT], qy2[QPT], qz2[QPT], q2[QPT], mn[QPT];
#pragma unroll
    for (int k = 0; k < QPT; ++k) {
        float4 v = q[qbase + k * BLOCK + threadIdx.x];
        qx2[k] = -2.0f * v.x;
        qy2[k] = -2.0f * v.y;
        qz2[k] = -2.0f * v.z;
        q2[k]  = v.w;
        mn[k]  = 3.4e38f;
    }
    __syncthreads();

    // Two db points per iteration; fminf(fminf()) -> v_min3_f32
#pragma unroll 2
    for (int j = 0; j < CHUNK; j += 2) {
        float4 p0 = tile[j];
        float4 p1 = tile[j + 1];
#pragma unroll
        for (int k = 0; k < QPT; ++k) {
            float a0 = fmaf(qx2[k], p0.x, p0.w);
            a0 = fmaf(qy2[k], p0.y, a0);
            a0 = fmaf(qz2[k], p0.z, a0);
            float a1 = fmaf(qx2[k], p1.x, p1.w);
            a1 = fmaf(qy2[k], p1.y, a1);
            a1 = fmaf(qz2[k], p1.z, a1);
            mn[k] = fminf(mn[k], fminf(a0, a1));
        }
    }

    // d2 = max(mn + q2, 0) >= 0, so uint compare == float compare
#pragma unroll
    for (int k = 0; k < QPT; ++k) {
        float d = fmaxf(mn[k] + q2[k], 0.0f);
        atomicMin(&minOut[qbase + k * BLOCK + threadIdx.x], __float_as_uint(d));
    }
}

// Multi-block reduce: block partial sums -> one atomicAdd per block.
#define RBLOCKS 128
__global__ __launch_bounds__(BLOCK) void chamfer_reduce(
    const unsigned* __restrict__ minC, const unsigned* __restrict__ minT,
    float* __restrict__ out, int n, int m)
{
    __shared__ float red[4];
    float s = 0.0f;
    const float invn = 1.0f / (float)n, invm = 1.0f / (float)m;
    for (int i = blockIdx.x * BLOCK + threadIdx.x; i < n; i += RBLOCKS * BLOCK)
        s += __uint_as_float(minC[i]) * invn;
    for (int i = blockIdx.x * BLOCK + threadIdx.x; i < m; i += RBLOCKS * BLOCK)
        s += __uint_as_float(minT[i]) * invm;

#pragma unroll
    for (int off = 32; off > 0; off >>= 1) s += __shfl_down(s, off, 64);
    int wave = threadIdx.x >> 6;
    int lane = threadIdx.x & 63;
    if (lane == 0) red[wave] = s;
    __syncthreads();
    if (threadIdx.x == 0) {
        float t = red[0] + red[1] + red[2] + red[3];
        atomicAdd(out, t);
    }
}

extern "C" void kernel_launch(void* const* d_in, const int* in_sizes, int n_in,
                              void* d_out, int out_size, void* d_ws, size_t ws_size,
                              hipStream_t stream) {
    const float* Xc = (const float*)d_in[0];
    const float* Xt = (const float*)d_in[1];
    const int n = in_sizes[0] / 3;   // 16384
    const int m = in_sizes[1] / 3;   // 16384

    // ws layout: minC[n] u32 | minT[m] u32 | Pc[n] float4 | Pt[m] float4
    unsigned* minC = (unsigned*)d_ws;
    unsigned* minT = minC + n;
    float4*   Pc   = (float4*)((char*)d_ws + (size_t)(n + m) * sizeof(unsigned));
    float4*   Pt   = Pc + n;
    float*    out  = (float*)d_out;

    int prepBlocks = ((n > m ? n : m) + BLOCK - 1) / BLOCK;
    chamfer_prep<<<prepBlocks, BLOCK, 0, stream>>>(Xc, Xt, Pc, Pt, minC, minT, out, n, m);

    dim3 grid(n / (BLOCK * QPT), DCHUNKS, 2);   // 8 x 128 x 2 = 2048 blocks
    chamfer_pass<<<grid, BLOCK, 0, stream>>>(Pc, Pt, minC, minT);

    chamfer_reduce<<<RBLOCKS, BLOCK, 0, stream>>>(minC, minT, out, n, m);
}